// Round 7
// baseline (128.916 us; speedup 1.0000x reference)
//
#include <hip/hip_runtime.h>

#define NEGF (-1e30f)
#define INV_LN2 1.4426950408889634f
#define LN2F    0.6931471805599453f

// Problem constants (from setup_inputs: B=8, T=128, U=64, V=1024)
#define B_   8
#define T_   128
#define U_   64
#define U1_  65
#define V_   1024
#define NDIAG_ 208              // >= T+U (192) + prefetch margin, in-bounds for deep refills
#define DS_    66               // float2 slots per diagonal (u in [0,64] for .x, [1,65] for .y)
#define PACKB_ (NDIAG_*DS_)     // float2 per batch
#define SLABS_ (T_*B_)          // 1024 per-(b,t) slab counters
#define BPS_   17               // k1 blocks per slab = ceil(65/4)
#define K1_BLOCKS_ (SLABS_*BPS_)  // 17408
#define WPS_   (BPS_*4)         // waves per slab = 68 (incl. idle waves)

typedef float f32x4 __attribute__((ext_vector_type(4)));

// lane l receives lane l-1's value; lane 0 keeps its own (DPP wave_shr:1).
__device__ __forceinline__ float wave_shr1(float x) {
  return __int_as_float(__builtin_amdgcn_update_dpp(
      __float_as_int(x), __float_as_int(x), 0x138, 0xf, 0xf, 0));
}

// One fused kernel.
//  blocks [0,8):        DP chasers, one per batch. Spin on slab counters,
//                       read diagonal-packed lp values from L2/L3 with
//                       depth-8 register prefetch.
//  blocks [8,8+17408):  log-softmax producers. Block j of slab (t,b) does
//                       u-rows 4j..4j+3; zero LDS -> full occupancy.
// pack[b][g][i] layout: .x = lpb[t][u] at (g=t+u, i=u); .y = lpl[t][u-1] at
// (g=t+u-1... i.e. cell (t,u') stored at g=t+u', i=u'+1). DP step dc reads
// diag g=dc-1: lane l (u=l+1) gets (.x=lpb[t-1][u], .y=lpl[t][u-1]) in ONE
// coalesced float2; feed lpb[dc-1][0] is a broadcast dword of the same diag.
__global__ __launch_bounds__(256) void rnnt_all(
    const float* __restrict__ acts, const int* __restrict__ labels,
    const int* __restrict__ act_lens, const int* __restrict__ label_lens,
    float2* __restrict__ pack, float* __restrict__ costs,
    int* __restrict__ cnt, int* __restrict__ done, float* __restrict__ out) {

  const int bid = (int)blockIdx.x;

  if (bid >= B_) {
    // ------------------------- k1: producer -------------------------
    const int kb   = bid - B_;
    const int sid  = kb / BPS_;                    // slab id = t*8 + b
    const int j    = kb - sid * BPS_;
    const int t    = sid >> 3;
    const int b    = sid & 7;
    const int lane = threadIdx.x & 63;
    const int w    = threadIdx.x >> 6;
    const int u    = 4 * j + w;

    if (u < U1_) {
      const float* __restrict__ p =
          acts + (size_t)((b * T_ + t) * U1_ + u) * V_;

      // hoisted label-path loads (lane 0 only)
      int ll_ = 0; float labv = 0.0f;
      if (lane == 0 && u < U_) {
        ll_  = label_lens[b];
        labv = p[labels[b * U_ + u]];              // in [1, V)
      }

      f32x4 v0 = *(const f32x4*)(p +   0 + lane * 4);
      f32x4 v1 = *(const f32x4*)(p + 256 + lane * 4);
      f32x4 v2 = *(const f32x4*)(p + 512 + lane * 4);
      f32x4 v3 = *(const f32x4*)(p + 768 + lane * 4);

      float m = fmaxf(fmaxf(fmaxf(v0.x, v0.y), fmaxf(v0.z, v0.w)),
                fmaxf(fmaxf(fmaxf(v1.x, v1.y), fmaxf(v1.z, v1.w)),
                fmaxf(fmaxf(fmaxf(v2.x, v2.y), fmaxf(v2.z, v2.w)),
                      fmaxf(fmaxf(v3.x, v3.y), fmaxf(v3.z, v3.w)))));
      #pragma unroll
      for (int o = 32; o; o >>= 1) m = fmaxf(m, __shfl_xor(m, o, 64));

      float s = __expf(v0.x - m) + __expf(v0.y - m) + __expf(v0.z - m) + __expf(v0.w - m)
              + __expf(v1.x - m) + __expf(v1.y - m) + __expf(v1.z - m) + __expf(v1.w - m)
              + __expf(v2.x - m) + __expf(v2.y - m) + __expf(v2.z - m) + __expf(v2.w - m)
              + __expf(v3.x - m) + __expf(v3.y - m) + __expf(v3.z - m) + __expf(v3.w - m);
      #pragma unroll
      for (int o = 32; o; o >>= 1) s += __shfl_xor(s, o, 64);

      float lse = m + __logf(s);                   // s >= 1

      if (lane == 0) {
        float2* pg = pack + (size_t)b * PACKB_ + (size_t)(t + u) * DS_;
        __hip_atomic_store(&pg[u].x, (v0.x - lse) * INV_LN2,
                           __ATOMIC_RELAXED, __HIP_MEMORY_SCOPE_AGENT);
        if (u < U_) {
          float val = (u < ll_) ? ((labv - lse) * INV_LN2) : NEGF;
          __hip_atomic_store(&pg[u + 1].y, val,
                             __ATOMIC_RELAXED, __HIP_MEMORY_SCOPE_AGENT);
        }
      }
    }
    // per-wave completion signal (idle waves too: counter target is 68)
    if (lane == 0) {
      asm volatile("s_waitcnt vmcnt(0)" ::: "memory");
      __hip_atomic_fetch_add(&cnt[sid], 1,
                             __ATOMIC_RELAXED, __HIP_MEMORY_SCOPE_AGENT);
    }
    return;
  }

  // ------------------------- DP: consumer -------------------------
  if (threadIdx.x >= 64) return;
  const int l  = (int)threadIdx.x;
  const int b  = bid;
  const int tl = act_lens[b] - 1;
  const int ll = label_lens[b];
  const float2* __restrict__ pk = pack + (size_t)b * PACKB_;

  const int  u    = l + 1;
  const bool isme = (u == ll);
  float a      = NEGF;
  float fin    = 0.0f;
  float pa0run = 0.0f;                             // alpha0[dc-1] on lane 0
  float a0cap  = 0.0f, fdcap = 0.0f;
  int   frontier = 0;                              // slabs [0,frontier) ready

#define WAITTO_(NEED) do {                                                   \
    int need_ = (NEED); if (need_ > T_ - 1) need_ = T_ - 1;                  \
    if (frontier <= need_) {                                                 \
      while (frontier <= need_) {                                            \
        int c_ = __hip_atomic_load(&cnt[frontier * B_ + b],                  \
                                   __ATOMIC_RELAXED, __HIP_MEMORY_SCOPE_AGENT); \
        if (c_ == WPS_) ++frontier; else __builtin_amdgcn_s_sleep(2);        \
      }                                                                      \
      __threadfence();  /* acquire: invalidate stale lines */                \
    }                                                                        \
  } while (0)

#define STEP_(DC, Q, F) do {                                          \
    int t_ = (DC) - u;                                                \
    float left = wave_shr1(a);                                        \
    left = (l == 0) ? pa0run : left;                                  \
    float blank  = a + (Q).x;                                         \
    float labelv = left + (Q).y;                                      \
    float mx = fmaxf(blank, labelv);                                  \
    float mn = fminf(blank, labelv);                                  \
    float e_; asm("v_exp_f32 %0, %1" : "=v"(e_) : "v"(mn - mx));      \
    float g_; asm("v_log_f32 %0, %1" : "=v"(g_) : "v"(1.0f + e_));    \
    float anew = mx + g_;                                             \
    bool valid = ((unsigned)t_ < (unsigned)T_);                       \
    a = valid ? anew : NEGF;                                          \
    fin   = (isme && t_ == tl)        ? a      : fin;                 \
    a0cap = (l == 0 && (DC) == tl + 1) ? pa0run : a0cap;              \
    fdcap = (l == 0 && (DC) == tl + 1) ? (F)    : fdcap;              \
    pa0run += (F);                                                    \
  } while (0)

  // prologue: slabs up to 15 cover prologue loads (diag<=7) and first
  // iteration's refills (diag<=15)
  WAITTO_(15);
  float2 q0 = pk[0 * DS_ + u], q1 = pk[1 * DS_ + u], q2 = pk[2 * DS_ + u], q3 = pk[3 * DS_ + u];
  float2 q4 = pk[4 * DS_ + u], q5 = pk[5 * DS_ + u], q6 = pk[6 * DS_ + u], q7 = pk[7 * DS_ + u];
  float  f0 = pk[0 * DS_].x, f1 = pk[1 * DS_].x, f2 = pk[2 * DS_].x, f3 = pk[3 * DS_].x;
  float  f4 = pk[4 * DS_].x, f5 = pk[5 * DS_].x, f6 = pk[6 * DS_].x, f7 = pk[7 * DS_].x;

  #pragma unroll 1
  for (int d = 1; d <= 185; d += 8) {              // steps d..d+7; 24 iters covers dc=1..192
    WAITTO_(d + 14);                               // refills touch diag <= d+14
    const float2* pd = pk + (size_t)(d + 7) * DS_;
    STEP_(d + 0, q0, f0); q0 = pd[0 * DS_ + u]; f0 = pd[0 * DS_].x;
    STEP_(d + 1, q1, f1); q1 = pd[1 * DS_ + u]; f1 = pd[1 * DS_].x;
    STEP_(d + 2, q2, f2); q2 = pd[2 * DS_ + u]; f2 = pd[2 * DS_].x;
    STEP_(d + 3, q3, f3); q3 = pd[3 * DS_ + u]; f3 = pd[3 * DS_].x;
    STEP_(d + 4, q4, f4); q4 = pd[4 * DS_ + u]; f4 = pd[4 * DS_].x;
    STEP_(d + 5, q5, f5); q5 = pd[5 * DS_ + u]; f5 = pd[5 * DS_].x;
    STEP_(d + 6, q6, f6); q6 = pd[6 * DS_ + u]; f6 = pd[6 * DS_].x;
    STEP_(d + 7, q7, f7); q7 = pd[7 * DS_ + u]; f7 = pd[7 * DS_].x;
  }
#undef STEP_
#undef WAITTO_

  if (isme) {                                      // exactly one lane (ll in [32,64])
    float vlast = pk[(size_t)(tl + ll) * DS_ + ll].x;   // lpb[tl][ll] (log2 dom)
    __hip_atomic_store(&costs[b], -(fin + vlast) * LN2F,
                       __ATOMIC_RELAXED, __HIP_MEMORY_SCOPE_AGENT);
  }
  if (l == 0 && ll == 0) {                         // vestigial safety path
    __hip_atomic_store(&costs[b], -(a0cap + fdcap) * LN2F,
                       __ATOMIC_RELAXED, __HIP_MEMORY_SCOPE_AGENT);
  }

  asm volatile("s_waitcnt vmcnt(0)" ::: "memory");
  if (l == 0) {
    int o = __hip_atomic_fetch_add(done, 1, __ATOMIC_RELAXED, __HIP_MEMORY_SCOPE_AGENT);
    if (o == B_ - 1) {                             // last DP block sums (deterministic)
      __threadfence();
      float s = 0.0f;
      #pragma unroll
      for (int i = 0; i < B_; ++i)
        s += __hip_atomic_load(&costs[i], __ATOMIC_RELAXED, __HIP_MEMORY_SCOPE_AGENT);
      out[0] = s;
    }
  }
}

extern "C" void kernel_launch(void* const* d_in, const int* in_sizes, int n_in,
                              void* d_out, int out_size, void* d_ws, size_t ws_size,
                              hipStream_t stream) {
  const float* acts       = (const float*)d_in[0];
  const int*   labels     = (const int*)d_in[1];
  const int*   act_lens   = (const int*)d_in[2];
  const int*   label_lens = (const int*)d_in[3];

  float2* pack  = (float2*)d_ws;                   // 8 * 13728 float2 = 878,592 B
  float*  costs = (float*)(pack + (size_t)B_ * PACKB_);
  int*    cnt   = (int*)(costs + B_);              // 1024 slab counters
  int*    done  = cnt + SLABS_;                    // 1 int

  hipMemsetAsync(cnt, 0, (SLABS_ + 1) * sizeof(int), stream);
  rnnt_all<<<B_ + K1_BLOCKS_, 256, 0, stream>>>(acts, labels, act_lens, label_lens,
                                                pack, costs, cnt, done, (float*)d_out);
}

// Round 8
// 65.650 us; speedup vs baseline: 1.9637x; 1.9637x over previous
//
#include <hip/hip_runtime.h>

#define NEGF (-1e30f)
#define INV_LN2 1.4426950408889634f
#define LN2F    0.6931471805599453f

// Problem constants (from setup_inputs: B=8, T=128, U=64, V=1024)
#define B_   8
#define T_   128
#define U_   64
#define U1_  65
#define V_   1024
#define PAD_ 66                 // padded row stride for lpb/lpl
#define ROWS_ (B_*T_*U1_)       // 66560
#define WS_PER_ (T_*PAD_)       // 8448 floats per batch per array

typedef float f32x4 __attribute__((ext_vector_type(4)));

// f64 lane shift: lane l receives lane l-1's value; lane 0 receives +0.0
// (bound_ctrl=1 zero-fills, and old=0 either way). Two 32-bit DPP ops.
__device__ __forceinline__ double shr1_f64(double x) {
  union { double d; int i[2]; } s, r;
  s.d = x;
  r.i[0] = __builtin_amdgcn_update_dpp(0, s.i[0], 0x138, 0xf, 0xf, true);
  r.i[1] = __builtin_amdgcn_update_dpp(0, s.i[1], 0x138, 0xf, 0xf, true);
  return r.d;
}

// ---------------------------------------------------------------------------
// K1: R2/R6 wave-per-row log-softmax (known-good). Emits LOG2-domain values.
// ---------------------------------------------------------------------------
__global__ __launch_bounds__(256) void k1_logsoftmax(
    const float* __restrict__ acts, const int* __restrict__ labels,
    const int* __restrict__ label_lens,
    float* __restrict__ lpb, float* __restrict__ lpl, int* __restrict__ cnt) {
  const int lane = threadIdx.x & 63;
  const int wv   = threadIdx.x >> 6;
  const int row  = blockIdx.x * 4 + wv;

  if (blockIdx.x == 0 && threadIdx.x == 0) *cnt = 0;   // k2's completion counter

  const int b   = row / (T_ * U1_);
  const int rem = row - b * (T_ * U1_);
  const int t   = rem / U1_;
  const int u   = rem - t * U1_;

  const float* __restrict__ p = acts + (size_t)row * V_;

  // hoisted label-path loads (lane 0 only); overlap with row load + reductions
  int ll_ = 0; float labv = 0.0f;
  if (lane == 0 && u < U_) {
    ll_  = label_lens[b];
    labv = p[labels[b * U_ + u]];                  // in [1, V)
  }

  f32x4 v0 = *(const f32x4*)(p +   0 + lane * 4);
  f32x4 v1 = *(const f32x4*)(p + 256 + lane * 4);
  f32x4 v2 = *(const f32x4*)(p + 512 + lane * 4);
  f32x4 v3 = *(const f32x4*)(p + 768 + lane * 4);

  float m = fmaxf(fmaxf(fmaxf(v0.x, v0.y), fmaxf(v0.z, v0.w)),
            fmaxf(fmaxf(fmaxf(v1.x, v1.y), fmaxf(v1.z, v1.w)),
            fmaxf(fmaxf(fmaxf(v2.x, v2.y), fmaxf(v2.z, v2.w)),
                  fmaxf(fmaxf(v3.x, v3.y), fmaxf(v3.z, v3.w)))));
  #pragma unroll
  for (int o = 32; o; o >>= 1) m = fmaxf(m, __shfl_xor(m, o, 64));

  float s = __expf(v0.x - m) + __expf(v0.y - m) + __expf(v0.z - m) + __expf(v0.w - m)
          + __expf(v1.x - m) + __expf(v1.y - m) + __expf(v1.z - m) + __expf(v1.w - m)
          + __expf(v2.x - m) + __expf(v2.y - m) + __expf(v2.z - m) + __expf(v2.w - m)
          + __expf(v3.x - m) + __expf(v3.y - m) + __expf(v3.z - m) + __expf(v3.w - m);
  #pragma unroll
  for (int o = 32; o; o >>= 1) s += __shfl_xor(s, o, 64);

  float lse = m + __logf(s);                       // s >= 1

  if (lane == 0) {
    int base = (b * T_ + t) * PAD_;
    lpb[base + u] = (v0.x - lse) * INV_LN2;        // log2 domain
    if (u < U_) lpl[base + u] = (u < ll_) ? ((labv - lse) * INV_LN2) : NEGF;
  }
}

// ---------------------------------------------------------------------------
// K2: anti-diagonal DP in the PROBABILITY domain (f64), no transcendentals
//     on the chain: a = fma(a,Pb, fma(shift(a),Pl, inj)). Staging converts
//     log2->linear f32 in LDS (wave-parallel). Exponent renorm every 32
//     steps is folded into the next step's constants (zero chain cost).
//     Boundary column u=0 enters via the multiplicative side-chain i0
//     (nonzero only on lane 0 by construction).
// ---------------------------------------------------------------------------
__global__ __launch_bounds__(256) void k2_alpha(
    const float* __restrict__ lpb, const float* __restrict__ lpl,
    const int* __restrict__ act_lens, const int* __restrict__ label_lens,
    float* __restrict__ costs, int* __restrict__ cnt, float* __restrict__ out) {
  __shared__ float pbl_s[WS_PER_];                 // 2^lpb  (linear blank probs)
  __shared__ float pll_s[WS_PER_];                 // 2^lpl  (linear label probs; NEGF -> 0)
  const int b = blockIdx.x;

  {  // stage + exp2-convert (float4 flat copy; batch base 16B aligned)
    const f32x4* s1 = (const f32x4*)(lpb + (size_t)b * WS_PER_);
    const f32x4* s2 = (const f32x4*)(lpl + (size_t)b * WS_PER_);
    #pragma unroll
    for (int k = 0; k < 9; ++k) {                  // 9*256 >= 2112
      int i = k * 256 + (int)threadIdx.x;
      if (i < WS_PER_ / 4) {
        f32x4 x = s1[i], y = s2[i], xo, yo;
        xo.x = exp2f(x.x); xo.y = exp2f(x.y); xo.z = exp2f(x.z); xo.w = exp2f(x.w);
        yo.x = exp2f(y.x); yo.y = exp2f(y.y); yo.z = exp2f(y.z); yo.w = exp2f(y.w);
        ((f32x4*)pbl_s)[i] = xo;
        ((f32x4*)pll_s)[i] = yo;
      }
    }
  }
  __syncthreads();
  if (threadIdx.x >= 64) return;

  const int l  = (int)threadIdx.x;
  const int tl = act_lens[b] - 1;                  // in [63,127]
  const int ll = label_lens[b];                    // in [32,64]
  const int u  = l + 1;
  const int dcap = (u == ll) ? (tl + ll) : 0x7fffffff;

  double a  = 0.0;
  double i0 = (l == 0) ? 1.0 : 0.0;                // 2^(alpha0[dc-1]-Ecum); 0 on l>0 forever
  double fin = 0.0;
  int Ecap = 0, Ecum = 0;

  // double-buffered 8-step operand blocks (all indices clamped -> always safe)
  float pbA[8], plA[8], b0A[8], l0A[8];
  float pbB[8], plB[8], b0B[8], l0B[8];

#define LOAD8_(K, PB, PL, B0, L0) do {                                   \
    _Pragma("unroll")                                                    \
    for (int j = 0; j < 8; ++j) {                                        \
      int dc = 8 * (K) + 1 + j;                                          \
      int rb = min(max(dc - u - 1, 0), T_ - 1);                          \
      int rl = min(max(dc - u,     0), T_ - 1);                          \
      int r0 = min(dc - 1, T_ - 1);                                      \
      (PB)[j] = pbl_s[rb * PAD_ + u];                                    \
      (PL)[j] = pll_s[rl * PAD_ + (u - 1)];                              \
      (B0)[j] = pbl_s[r0 * PAD_];                                        \
      (L0)[j] = pll_s[r0 * PAD_];                                        \
    }                                                                    \
  } while (0)

  LOAD8_(0, pbA, plA, b0A, l0A);

  #pragma unroll 1
  for (int k = 0; k < 24; ++k) {                   // dc = 8k+1 .. 8k+8 (1..192)
    LOAD8_(k + 1, pbB, plB, b0B, l0B);             // prefetch next block (clamps keep it safe)

    double sc = 1.0;
    if ((k & 3) == 0 && k > 0) {                   // renorm every 32 steps (k=4,8,12,16,20)
      int e_ = (a != 0.0) ? ilogb(a) : -30000;
      e_ = min(max(e_, -30000), 30000);
      #pragma unroll
      for (int o = 32; o; o >>= 1) e_ = max(e_, __shfl_xor(e_, o, 64));
      Ecum += e_;
      sc = ldexp(1.0, -e_);                        // fold 2^-E into step-0 constants
      i0 *= sc;
    }

    #pragma unroll
    for (int j = 0; j < 8; ++j) {
      const int dc = 8 * k + 1 + j;
      double pb64 = (double)pbA[j];
      double pl64 = (double)plA[j];
      if (j == 0) { pb64 *= sc; pl64 *= sc; }      // renorm enters every path exactly once
      double inj  = i0 * (double)l0A[j];           // boundary: alpha[dc-1][0]*Pl[dc-1][0]
      double shin = shr1_f64(a);                   // alpha[t][u-1] rel Ecum (0 into lane 0)
      a = fma(a, pb64, fma(shin, pl64, inj));
      if (dc == dcap) { fin = a; Ecap = Ecum; }    // alpha[tl][ll]
      i0 *= (double)b0A[j];                        // advance alpha0 side-chain
    }

    #pragma unroll
    for (int j = 0; j < 8; ++j) {
      pbA[j] = pbB[j]; plA[j] = plB[j]; b0A[j] = b0B[j]; l0A[j] = l0B[j];
    }
  }
#undef LOAD8_

  if (u == ll) {                                   // exactly one lane (ll in [32,64])
    double lg = (double)Ecap + log2(fin)
              + (double)log2f(pbl_s[tl * PAD_ + ll]);
    costs[b] = (float)(-lg * (double)LN2F);
  }

  // last block to arrive sums the 8 costs (deterministic: single writer)
  __threadfence();
  if (l == 0) {
    int old = atomicAdd(cnt, 1);
    if (old == B_ - 1) {
      __threadfence();
      volatile const float* vc = costs;
      float s = 0.0f;
      #pragma unroll
      for (int i = 0; i < B_; ++i) s += vc[i];
      out[0] = s;
    }
  }
}

extern "C" void kernel_launch(void* const* d_in, const int* in_sizes, int n_in,
                              void* d_out, int out_size, void* d_ws, size_t ws_size,
                              hipStream_t stream) {
  const float* acts       = (const float*)d_in[0];
  const int*   labels     = (const int*)d_in[1];
  const int*   act_lens   = (const int*)d_in[2];
  const int*   label_lens = (const int*)d_in[3];

  float* lpb   = (float*)d_ws;                       // B*T*PAD floats
  float* lpl   = lpb + (size_t)B_ * WS_PER_;         // B*T*PAD floats
  float* costs = lpl + (size_t)B_ * WS_PER_;         // B floats
  int*   cnt   = (int*)(costs + B_);                 // 1 int

  k1_logsoftmax<<<ROWS_ / 4, 256, 0, stream>>>(acts, labels, label_lens, lpb, lpl, cnt);
  k2_alpha<<<B_, 256, 0, stream>>>(lpb, lpl, act_lens, label_lens, costs, cnt, (float*)d_out);
}